// Round 1
// baseline (1017.667 us; speedup 1.0000x reference)
//
#include <hip/hip_runtime.h>
#include <cstdint>

// Problem constants (fixed by the reference: B=64,S=512,IN=OUT=256,R=40,NB=3,E=262144)
#define N_NODES 32768
#define IN_F    256
#define OUT_F   256
#define NBASES  3
#define N_EDGES 262144
#define T_COLS  (NBASES * OUT_F)   // 768

typedef __attribute__((ext_vector_type(8))) short bf16x8;
typedef __attribute__((ext_vector_type(4))) float f32x4;

__device__ __forceinline__ unsigned short f2bf(float x) {
    union { float f; unsigned int u; } c; c.f = x;
    unsigned int u = c.u;
    u = (u + 0x7FFFu + ((u >> 16) & 1u)) >> 16;   // round-to-nearest-even
    return (unsigned short)u;
}
__device__ __forceinline__ float bf2f(unsigned short h) {
    union { unsigned int u; float f; } c; c.u = ((unsigned int)h) << 16;
    return c.f;
}

// ---------------------------------------------------------------------------
// Kernel 1: t[n, b, o] = sum_i h[n,i] * bases[b,i,o]   (bf16 MFMA, f32 accum)
// Grid: (N_NODES/128, OUT_F/128, NBASES), block 256 (4 waves, 2x2 wave grid,
// each wave owns a 64x64 sub-tile = 4x4 MFMA 16x16x32 tiles).
// ---------------------------------------------------------------------------
__global__ __launch_bounds__(256) void proj_kernel(
    const float* __restrict__ h,      // [N_NODES, IN_F] f32
    const float* __restrict__ bases,  // [NBASES, IN_F, OUT_F] f32
    unsigned short* __restrict__ t)   // [N_NODES, NBASES, OUT_F] bf16
{
    constexpr int BK  = 32;
    constexpr int LDK = 40;           // padded k-stride (80 B: 16B-aligned rows)
    __shared__ unsigned short As[128 * LDK];   // As[m][k]
    __shared__ unsigned short Bs[128 * LDK];   // Bs[n][k] (transposed, k-octet swizzled)

    const int mb = blockIdx.x, nb = blockIdx.y, bb = blockIdx.z;
    const float* W = bases + (size_t)bb * IN_F * OUT_F;   // [K=256][O=256] row-major
    const int tid  = threadIdx.x;
    const int wave = tid >> 6, lane = tid & 63;
    const int quad = lane >> 4, l16 = lane & 15;
    const int wm = (wave & 1) * 64, wn = (wave >> 1) * 64;
    const int m0 = mb * 128, n0 = nb * 128;

    f32x4 acc[4][4] = {};

    const int ar = tid >> 3;          // A stage: row 0..31 (+32*it)
    const int ac = (tid & 7) * 4;     // A stage: col
    const int bk = tid >> 5;          // B stage: k 0..7 (+8*it)
    const int bn = (tid & 31) * 4;    // B stage: n
    const int bswz = (bn >> 2) & 3;   // swizzle selector (function of n only)

    for (int k0 = 0; k0 < IN_F; k0 += BK) {
        // Stage A tile 128x32 (f32 -> bf16), coalesced float4 reads
        #pragma unroll
        for (int it = 0; it < 4; ++it) {
            int row = ar + it * 32;
            float4 v = *reinterpret_cast<const float4*>(
                h + (size_t)(m0 + row) * IN_F + k0 + ac);
            ushort4 p;
            p.x = f2bf(v.x); p.y = f2bf(v.y); p.z = f2bf(v.z); p.w = f2bf(v.w);
            *reinterpret_cast<ushort4*>(&As[row * LDK + ac]) = p;
        }
        // Stage B tile 32x128 transposed into Bs[n][k]; k-octet XOR-swizzle to
        // break the 16-way bank conflict the transpose writes would otherwise hit
        #pragma unroll
        for (int it = 0; it < 4; ++it) {
            int kk = bk + it * 8;
            float4 v = *reinterpret_cast<const float4*>(
                W + (size_t)(k0 + kk) * OUT_F + n0 + bn);
            int kcol = (((kk >> 3) ^ bswz) << 3) + (kk & 7);
            Bs[(bn + 0) * LDK + kcol] = f2bf(v.x);
            Bs[(bn + 1) * LDK + kcol] = f2bf(v.y);
            Bs[(bn + 2) * LDK + kcol] = f2bf(v.z);
            Bs[(bn + 3) * LDK + kcol] = f2bf(v.w);
        }
        __syncthreads();

        // Fragments: A[m = l16][k-octet = quad], B[n = l16][k-octet = quad]
        bf16x8 af[4], bfr[4];
        #pragma unroll
        for (int i = 0; i < 4; ++i) {
            af[i] = *reinterpret_cast<const bf16x8*>(
                &As[(wm + i * 16 + l16) * LDK + quad * 8]);
            int nn  = wn + i * 16 + l16;
            int oct = quad ^ ((nn >> 2) & 3);
            bfr[i] = *reinterpret_cast<const bf16x8*>(&Bs[nn * LDK + oct * 8]);
        }
        #pragma unroll
        for (int i = 0; i < 4; ++i)
            #pragma unroll
            for (int j = 0; j < 4; ++j)
                acc[i][j] = __builtin_amdgcn_mfma_f32_16x16x32_bf16(
                    af[i], bfr[j], acc[i][j], 0, 0, 0);
        __syncthreads();
    }

    // Epilogue: C/D layout col = l16, row = quad*4 + r. Store bf16 to t.
    #pragma unroll
    for (int i = 0; i < 4; ++i) {
        int node_base = m0 + wm + i * 16 + quad * 4;
        #pragma unroll
        for (int j = 0; j < 4; ++j) {
            int o = n0 + wn + j * 16 + l16;
            size_t base = (size_t)node_base * T_COLS + bb * OUT_F + o;
            #pragma unroll
            for (int r = 0; r < 4; ++r)
                t[base + (size_t)r * T_COLS] = f2bf(acc[i][j][r]);
        }
    }
}

// ---------------------------------------------------------------------------
// Kernel 2: per-edge msg = sum_b comp[rel,b] * t[src,b,:]; atomicAdd into agg[dst]
// One wave per edge; lane handles 4 contiguous outputs (ushort4 bf16 loads).
// ---------------------------------------------------------------------------
__global__ __launch_bounds__(256) void edge_kernel(
    const unsigned short* __restrict__ t,   // [N_NODES, 3, 256] bf16
    const int* __restrict__ src,
    const int* __restrict__ dst,
    const int* __restrict__ rel,
    const float* __restrict__ comp,         // [40, 3]
    float* __restrict__ agg)                // [N_NODES, 256] f32 (pre-zeroed)
{
    int e    = blockIdx.x * 4 + (threadIdx.x >> 6);
    int lane = threadIdx.x & 63;
    int s = __builtin_amdgcn_readfirstlane(src[e]);
    int d = __builtin_amdgcn_readfirstlane(dst[e]);
    int r = __builtin_amdgcn_readfirstlane(rel[e]);
    float c0 = comp[r * 3 + 0];
    float c1 = comp[r * 3 + 1];
    float c2 = comp[r * 3 + 2];

    const unsigned short* tp = t + (size_t)s * T_COLS + lane * 4;
    ushort4 a0 = *reinterpret_cast<const ushort4*>(tp);
    ushort4 a1 = *reinterpret_cast<const ushort4*>(tp + 256);
    ushort4 a2 = *reinterpret_cast<const ushort4*>(tp + 512);

    float* ap = agg + (size_t)d * OUT_F + lane * 4;
    atomicAdd(ap + 0, c0 * bf2f(a0.x) + c1 * bf2f(a1.x) + c2 * bf2f(a2.x));
    atomicAdd(ap + 1, c0 * bf2f(a0.y) + c1 * bf2f(a1.y) + c2 * bf2f(a2.y));
    atomicAdd(ap + 2, c0 * bf2f(a0.z) + c1 * bf2f(a1.z) + c2 * bf2f(a2.z));
    atomicAdd(ap + 3, c0 * bf2f(a0.w) + c1 * bf2f(a1.w) + c2 * bf2f(a2.w));
}

// ---------------------------------------------------------------------------
// Kernel 3: out = relu(agg + bias), in place, float4
// ---------------------------------------------------------------------------
__global__ __launch_bounds__(256) void finish_kernel(
    float* __restrict__ out, const float* __restrict__ bias)
{
    int i = blockIdx.x * 256 + threadIdx.x;          // float4 index
    float4 v = reinterpret_cast<float4*>(out)[i];
    float4 b = reinterpret_cast<const float4*>(bias)[i & 63];  // OUT_F/4 = 64
    v.x = fmaxf(v.x + b.x, 0.f);
    v.y = fmaxf(v.y + b.y, 0.f);
    v.z = fmaxf(v.z + b.z, 0.f);
    v.w = fmaxf(v.w + b.w, 0.f);
    reinterpret_cast<float4*>(out)[i] = v;
}

extern "C" void kernel_launch(void* const* d_in, const int* in_sizes, int n_in,
                              void* d_out, int out_size, void* d_ws, size_t ws_size,
                              hipStream_t stream) {
    const float* text  = (const float*)d_in[0];   // [64,512,256] f32
    const int*   src   = (const int*)d_in[1];     // [E]
    const int*   dst   = (const int*)d_in[2];     // [E]
    const int*   rel   = (const int*)d_in[3];     // [E]
    const float* bases = (const float*)d_in[4];   // [3,256,256] f32
    const float* comp  = (const float*)d_in[5];   // [40,3] f32
    const float* bias  = (const float*)d_in[6];   // [256] f32
    float* out = (float*)d_out;
    unsigned short* t = (unsigned short*)d_ws;    // needs 32768*768*2 = 50.3 MB

    // agg accumulates directly in d_out; it is re-poisoned before every launch,
    // so zero it here (memset-async is graph-capture safe).
    hipMemsetAsync(d_out, 0, (size_t)N_NODES * OUT_F * sizeof(float), stream);

    proj_kernel<<<dim3(N_NODES / 128, OUT_F / 128, NBASES), 256, 0, stream>>>(
        text, bases, t);
    edge_kernel<<<N_EDGES / 4, 256, 0, stream>>>(t, src, dst, rel, comp, out);
    finish_kernel<<<(N_NODES * OUT_F / 4) / 256, 256, 0, stream>>>(out, bias);
}

// Round 2
// 244.001 us; speedup vs baseline: 4.1707x; 4.1707x over previous
//
#include <hip/hip_runtime.h>
#include <cstdint>

// Problem constants (fixed by the reference: B=64,S=512,IN=OUT=256,R=40,NB=3,E=262144)
#define N_NODES 32768
#define IN_F    256
#define OUT_F   256
#define NBASES  3
#define N_EDGES 262144
#define T_COLS  (NBASES * OUT_F)   // 768

typedef __attribute__((ext_vector_type(8))) short bf16x8;
typedef __attribute__((ext_vector_type(4))) float f32x4;

__device__ __forceinline__ unsigned short f2bf(float x) {
    union { float f; unsigned int u; } c; c.f = x;
    unsigned int u = c.u;
    u = (u + 0x7FFFu + ((u >> 16) & 1u)) >> 16;   // round-to-nearest-even
    return (unsigned short)u;
}
__device__ __forceinline__ float bf2f(unsigned short h) {
    union { unsigned int u; float f; } c; c.u = ((unsigned int)h) << 16;
    return c.f;
}

// ---------------------------------------------------------------------------
// Kernel 1: t[n, b, o] = sum_i h[n,i] * bases[b,i,o]   (bf16 MFMA, f32 accum)
// ---------------------------------------------------------------------------
__global__ __launch_bounds__(256) void proj_kernel(
    const float* __restrict__ h,      // [N_NODES, IN_F] f32
    const float* __restrict__ bases,  // [NBASES, IN_F, OUT_F] f32
    unsigned short* __restrict__ t)   // [N_NODES, NBASES, OUT_F] bf16
{
    constexpr int BK  = 32;
    constexpr int LDK = 40;           // padded k-stride (80 B: 16B-aligned rows)
    __shared__ unsigned short As[128 * LDK];   // As[m][k]
    __shared__ unsigned short Bs[128 * LDK];   // Bs[n][k] (transposed, k-octet swizzled)

    const int mb = blockIdx.x, nb = blockIdx.y, bb = blockIdx.z;
    const float* W = bases + (size_t)bb * IN_F * OUT_F;   // [K=256][O=256] row-major
    const int tid  = threadIdx.x;
    const int wave = tid >> 6, lane = tid & 63;
    const int quad = lane >> 4, l16 = lane & 15;
    const int wm = (wave & 1) * 64, wn = (wave >> 1) * 64;
    const int m0 = mb * 128, n0 = nb * 128;

    f32x4 acc[4][4] = {};

    const int ar = tid >> 3;          // A stage: row 0..31 (+32*it)
    const int ac = (tid & 7) * 4;     // A stage: col
    const int bk = tid >> 5;          // B stage: k 0..7 (+8*it)
    const int bn = (tid & 31) * 4;    // B stage: n
    const int bswz = (bn >> 2) & 3;   // swizzle selector (function of n only)

    for (int k0 = 0; k0 < IN_F; k0 += BK) {
        #pragma unroll
        for (int it = 0; it < 4; ++it) {
            int row = ar + it * 32;
            float4 v = *reinterpret_cast<const float4*>(
                h + (size_t)(m0 + row) * IN_F + k0 + ac);
            ushort4 p;
            p.x = f2bf(v.x); p.y = f2bf(v.y); p.z = f2bf(v.z); p.w = f2bf(v.w);
            *reinterpret_cast<ushort4*>(&As[row * LDK + ac]) = p;
        }
        #pragma unroll
        for (int it = 0; it < 4; ++it) {
            int kk = bk + it * 8;
            float4 v = *reinterpret_cast<const float4*>(
                W + (size_t)(k0 + kk) * OUT_F + n0 + bn);
            int kcol = (((kk >> 3) ^ bswz) << 3) + (kk & 7);
            Bs[(bn + 0) * LDK + kcol] = f2bf(v.x);
            Bs[(bn + 1) * LDK + kcol] = f2bf(v.y);
            Bs[(bn + 2) * LDK + kcol] = f2bf(v.z);
            Bs[(bn + 3) * LDK + kcol] = f2bf(v.w);
        }
        __syncthreads();

        bf16x8 af[4], bfr[4];
        #pragma unroll
        for (int i = 0; i < 4; ++i) {
            af[i] = *reinterpret_cast<const bf16x8*>(
                &As[(wm + i * 16 + l16) * LDK + quad * 8]);
            int nn  = wn + i * 16 + l16;
            int oct = quad ^ ((nn >> 2) & 3);
            bfr[i] = *reinterpret_cast<const bf16x8*>(&Bs[nn * LDK + oct * 8]);
        }
        #pragma unroll
        for (int i = 0; i < 4; ++i)
            #pragma unroll
            for (int j = 0; j < 4; ++j)
                acc[i][j] = __builtin_amdgcn_mfma_f32_16x16x32_bf16(
                    af[i], bfr[j], acc[i][j], 0, 0, 0);
        __syncthreads();
    }

    #pragma unroll
    for (int i = 0; i < 4; ++i) {
        int node_base = m0 + wm + i * 16 + quad * 4;
        #pragma unroll
        for (int j = 0; j < 4; ++j) {
            int o = n0 + wn + j * 16 + l16;
            size_t base = (size_t)node_base * T_COLS + bb * OUT_F + o;
            #pragma unroll
            for (int r = 0; r < 4; ++r)
                t[base + (size_t)r * T_COLS] = f2bf(acc[i][j][r]);
        }
    }
}

// ---------------------------------------------------------------------------
// Counting sort of edges by dst: histogram -> scan -> scatter
// ---------------------------------------------------------------------------
__global__ __launch_bounds__(256) void hist_kernel(
    const int* __restrict__ dst, int* __restrict__ counts)
{
    int e = blockIdx.x * 256 + threadIdx.x;
    atomicAdd(&counts[dst[e]], 1);
}

// Single block, 256 threads, each owns 128 consecutive counters.
__global__ __launch_bounds__(256) void scan_kernel(
    const int* __restrict__ counts, int* __restrict__ offsets,
    int* __restrict__ cursor)
{
    __shared__ int part[256];
    const int tid = threadIdx.x;
    const int base = tid * 128;
    int sum = 0;
    for (int k = 0; k < 128; ++k) sum += counts[base + k];
    part[tid] = sum;
    __syncthreads();
    for (int off = 1; off < 256; off <<= 1) {
        int v = (tid >= off) ? part[tid - off] : 0;
        __syncthreads();
        part[tid] += v;
        __syncthreads();
    }
    int run = (tid == 0) ? 0 : part[tid - 1];
    for (int k = 0; k < 128; ++k) {
        int c = counts[base + k];
        offsets[base + k] = run;
        cursor[base + k] = run;
        run += c;
    }
    if (tid == 255) offsets[N_NODES] = run;   // == N_EDGES
}

__global__ __launch_bounds__(256) void scatter_kernel(
    const int* __restrict__ dst, int* __restrict__ cursor,
    int* __restrict__ order)
{
    int e = blockIdx.x * 256 + threadIdx.x;
    int pos = atomicAdd(&cursor[dst[e]], 1);
    order[pos] = e;
}

// ---------------------------------------------------------------------------
// Kernel 2: one wave per dst node. Segmented reduction over its edge list,
// accumulate 256 outputs in registers (4/lane), fused bias+ReLU, single
// non-atomic row write.
// ---------------------------------------------------------------------------
__global__ __launch_bounds__(256) void agg_kernel(
    const unsigned short* __restrict__ t,     // [N_NODES, 3, 256] bf16
    const int* __restrict__ src,
    const int* __restrict__ rel,
    const int* __restrict__ order,            // edge ids sorted by dst
    const int* __restrict__ offsets,          // [N_NODES+1]
    const float* __restrict__ comp,           // [40, 3]
    const float* __restrict__ bias,           // [256]
    float* __restrict__ out)                  // [N_NODES, 256]
{
    const int node = blockIdx.x * 4 + (threadIdx.x >> 6);
    const int lane = threadIdx.x & 63;
    const int start = offsets[node];
    const int end   = offsets[node + 1];

    float acc0 = 0.f, acc1 = 0.f, acc2 = 0.f, acc3 = 0.f;

    for (int cb = start; cb < end; cb += 64) {
        // Cooperative, coalesced chunk-load of edge metadata
        int idx = cb + lane;
        int sv = 0, rv = 0;
        if (idx < end) {
            int e = order[idx];
            sv = src[e];
            rv = rel[e];
        }
        int cnt = min(64, end - cb);
        for (int j = 0; j < cnt; ++j) {
            int s = __shfl(sv, j);
            int r = __shfl(rv, j);
            float c0 = comp[r * 3 + 0];
            float c1 = comp[r * 3 + 1];
            float c2 = comp[r * 3 + 2];
            const unsigned short* tp = t + (size_t)s * T_COLS + lane * 4;
            ushort4 a0 = *reinterpret_cast<const ushort4*>(tp);
            ushort4 a1 = *reinterpret_cast<const ushort4*>(tp + 256);
            ushort4 a2 = *reinterpret_cast<const ushort4*>(tp + 512);
            acc0 += c0 * bf2f(a0.x) + c1 * bf2f(a1.x) + c2 * bf2f(a2.x);
            acc1 += c0 * bf2f(a0.y) + c1 * bf2f(a1.y) + c2 * bf2f(a2.y);
            acc2 += c0 * bf2f(a0.z) + c1 * bf2f(a1.z) + c2 * bf2f(a2.z);
            acc3 += c0 * bf2f(a0.w) + c1 * bf2f(a1.w) + c2 * bf2f(a2.w);
        }
    }

    float4 b = reinterpret_cast<const float4*>(bias)[lane];
    float4 v;
    v.x = fmaxf(acc0 + b.x, 0.f);
    v.y = fmaxf(acc1 + b.y, 0.f);
    v.z = fmaxf(acc2 + b.z, 0.f);
    v.w = fmaxf(acc3 + b.w, 0.f);
    reinterpret_cast<float4*>(out + (size_t)node * OUT_F)[lane] = v;
}

extern "C" void kernel_launch(void* const* d_in, const int* in_sizes, int n_in,
                              void* d_out, int out_size, void* d_ws, size_t ws_size,
                              hipStream_t stream) {
    const float* text  = (const float*)d_in[0];   // [64,512,256] f32
    const int*   src   = (const int*)d_in[1];     // [E]
    const int*   dst   = (const int*)d_in[2];     // [E]
    const int*   rel   = (const int*)d_in[3];     // [E]
    const float* bases = (const float*)d_in[4];   // [3,256,256] f32
    const float* comp  = (const float*)d_in[5];   // [40,3] f32
    const float* bias  = (const float*)d_in[6];   // [256] f32
    float* out = (float*)d_out;

    // Workspace layout (~51.8 MB total)
    unsigned short* t = (unsigned short*)d_ws;                    // 50331648 B
    int* order   = (int*)((char*)d_ws + (size_t)N_NODES * T_COLS * 2); // E ints
    int* offsets = order + N_EDGES;                               // N+1 ints
    int* cursor  = offsets + (N_NODES + 1);                       // N ints
    int* counts  = cursor + N_NODES;                              // N ints

    hipMemsetAsync(counts, 0, (size_t)N_NODES * sizeof(int), stream);

    proj_kernel<<<dim3(N_NODES / 128, OUT_F / 128, NBASES), 256, 0, stream>>>(
        text, bases, t);
    hist_kernel<<<N_EDGES / 256, 256, 0, stream>>>(dst, counts);
    scan_kernel<<<1, 256, 0, stream>>>(counts, offsets, cursor);
    scatter_kernel<<<N_EDGES / 256, 256, 0, stream>>>(dst, cursor, order);
    agg_kernel<<<N_NODES / 4, 256, 0, stream>>>(
        t, src, rel, order, offsets, comp, bias, out);
}

// Round 3
// 215.270 us; speedup vs baseline: 4.7274x; 1.1335x over previous
//
#include <hip/hip_runtime.h>
#include <cstdint>

// Problem constants (fixed by the reference: B=64,S=512,IN=OUT=256,R=40,NB=3,E=262144)
#define N_NODES 32768
#define IN_F    256
#define OUT_F   256
#define NBASES  3
#define N_EDGES 262144
#define K_DIM   (NBASES * IN_F)    // 768: GEMM reduction dim (b*256 + i)

typedef __attribute__((ext_vector_type(8))) short bf16x8;
typedef __attribute__((ext_vector_type(4))) float f32x4;

__device__ __forceinline__ unsigned short f2bf(float x) {
    union { float f; unsigned int u; } c; c.f = x;
    unsigned int u = c.u;
    u = (u + 0x7FFFu + ((u >> 16) & 1u)) >> 16;   // round-to-nearest-even
    return (unsigned short)u;
}

__device__ __forceinline__ void async_copy16(const void* g, void* l) {
    __builtin_amdgcn_global_load_lds(
        (const __attribute__((address_space(1))) unsigned int*)g,
        (__attribute__((address_space(3))) unsigned int*)l, 16, 0, 0);
}

// ---------------------------------------------------------------------------
// Counting sort of edges by dst: histogram -> scan -> scatter(packed)
// ---------------------------------------------------------------------------
__global__ __launch_bounds__(256) void hist_kernel(
    const int* __restrict__ dst, int* __restrict__ counts)
{
    int e = blockIdx.x * 256 + threadIdx.x;
    atomicAdd(&counts[dst[e]], 1);
}

// Single block, 1024 threads, 32 counters each. Converts counts -> cursor
// in place and writes the exclusive-scan offsets.
__global__ __launch_bounds__(1024) void scan_kernel(
    int* __restrict__ counts,        // in: histogram; out: cursor (in place)
    int* __restrict__ offsets)       // [N_NODES+1]
{
    __shared__ int wsum[16];
    const int tid = threadIdx.x;
    const int wave = tid >> 6, lane = tid & 63;
    const int base = tid * 32;
    int local[32];
    int sum = 0;
    #pragma unroll
    for (int k = 0; k < 32; ++k) { local[k] = counts[base + k]; sum += local[k]; }
    int inc = sum;                            // wave-inclusive scan of sums
    #pragma unroll
    for (int off = 1; off < 64; off <<= 1) {
        int v = __shfl_up(inc, off);
        if (lane >= off) inc += v;
    }
    if (lane == 63) wsum[wave] = inc;
    __syncthreads();
    if (wave == 0 && lane < 16) {             // scan the 16 wave totals
        int v = wsum[lane];
        #pragma unroll
        for (int off = 1; off < 16; off <<= 1) {
            int u = __shfl_up(v, off);
            if (lane >= off) v += u;
        }
        wsum[lane] = v;
    }
    __syncthreads();
    int run = inc - sum + (wave ? wsum[wave - 1] : 0);   // exclusive prefix
    #pragma unroll
    for (int k = 0; k < 32; ++k) {
        offsets[base + k] = run;
        counts[base + k] = run;               // cursor
        run += local[k];
    }
    if (tid == 1023) offsets[N_NODES] = run;  // == N_EDGES
}

__global__ __launch_bounds__(256) void scatter_kernel(
    const int* __restrict__ dst, const int* __restrict__ src,
    const int* __restrict__ rel, int* __restrict__ cursor,
    int* __restrict__ packed)                 // sorted (rel<<16)|src
{
    int e = blockIdx.x * 256 + threadIdx.x;
    int pos = atomicAdd(&cursor[dst[e]], 1);
    packed[pos] = (rel[e] << 16) | src[e];
}

// ---------------------------------------------------------------------------
// Aggregation in INPUT space: z[n, b, i] = sum_{e: dst=n} comp[rel_e,b]*h[src_e,i]
// One wave per dst node; lane owns 4 input features; 12 f32 accumulators.
// Gathers h as float4 (16 B/lane/edge). Writes z bf16 [N, 3, 256].
// ---------------------------------------------------------------------------
__global__ __launch_bounds__(256) void agg_kernel(
    const float* __restrict__ h,              // [N_NODES, 256] f32
    const int* __restrict__ packed,           // sorted by dst
    const int* __restrict__ offsets,          // [N_NODES+1]
    const float* __restrict__ comp,           // [40, 3]
    unsigned short* __restrict__ z)           // [N_NODES, 768] bf16
{
    __shared__ float compS[128];
    if (threadIdx.x < 120) compS[threadIdx.x] = comp[threadIdx.x];
    __syncthreads();

    const int node = blockIdx.x * 4 + (threadIdx.x >> 6);
    const int lane = threadIdx.x & 63;
    const int start = offsets[node];
    const int end   = offsets[node + 1];

    float a0[4] = {}, a1[4] = {}, a2[4] = {};

    for (int cb = start; cb < end; cb += 64) {
        int idx = cb + lane;
        int pv = (idx < end) ? packed[idx] : 0;
        int cnt = min(64, end - cb);
        for (int j = 0; j < cnt; ++j) {
            int p = __shfl(pv, j);
            int s = p & 0xFFFF;
            int r = p >> 16;
            float c0 = compS[r * 3 + 0];
            float c1 = compS[r * 3 + 1];
            float c2 = compS[r * 3 + 2];
            float4 v = *reinterpret_cast<const float4*>(
                h + (size_t)s * IN_F + lane * 4);
            a0[0] += c0 * v.x; a0[1] += c0 * v.y; a0[2] += c0 * v.z; a0[3] += c0 * v.w;
            a1[0] += c1 * v.x; a1[1] += c1 * v.y; a1[2] += c1 * v.z; a1[3] += c1 * v.w;
            a2[0] += c2 * v.x; a2[1] += c2 * v.y; a2[2] += c2 * v.z; a2[3] += c2 * v.w;
        }
    }

    unsigned short* zp = z + (size_t)node * K_DIM + lane * 4;
    ushort4 o;
    o.x = f2bf(a0[0]); o.y = f2bf(a0[1]); o.z = f2bf(a0[2]); o.w = f2bf(a0[3]);
    *reinterpret_cast<ushort4*>(zp) = o;
    o.x = f2bf(a1[0]); o.y = f2bf(a1[1]); o.z = f2bf(a1[2]); o.w = f2bf(a1[3]);
    *reinterpret_cast<ushort4*>(zp + 256) = o;
    o.x = f2bf(a2[0]); o.y = f2bf(a2[1]); o.z = f2bf(a2[2]); o.w = f2bf(a2[3]);
    *reinterpret_cast<ushort4*>(zp + 512) = o;
}

// ---------------------------------------------------------------------------
// GEMM: out[m, o] = relu( sum_k z[m,k] * bases_flat[k,o] + bias[o] )
// M=32768, K=768, N=256. 128x128 tile, BK=32, 4 waves (2x2), MFMA 16x16x32.
// A (bf16) staged via global_load_lds width=16 into an XOR-swizzled LDS
// layout (2-way max bank aliasing = free). B (f32) staged via VALU transpose
// with k-octet swizzle (proven in R1/R2 proj_kernel).
// ---------------------------------------------------------------------------
__global__ __launch_bounds__(256) void gemm_kernel(
    const unsigned short* __restrict__ A,   // z [32768, 768] bf16
    const float* __restrict__ Wf,           // bases [768, 256] f32 (flat)
    const float* __restrict__ bias,         // [256]
    float* __restrict__ out)                // [32768, 256] f32
{
    constexpr int BK  = 32;
    constexpr int LDK = 40;
    __shared__ __align__(16) unsigned short As[128 * 32];   // 16B slots, swizzled
    __shared__ unsigned short Bs[128 * LDK];

    const int tid  = threadIdx.x;
    const int wave = tid >> 6, lane = tid & 63;
    const int quad = lane >> 4, l16 = lane & 15;
    const int wm = (wave & 1) * 64, wn = (wave >> 1) * 64;
    const int m0 = blockIdx.x * 128, n0 = blockIdx.y * 128;

    f32x4 acc[4][4] = {};

    // A staging: 512 16-B slots; slot p <- logical (row = p>>2, oct = (p&3)^((row>>1)&3))
    // Each wave issues 2 global_load_lds of 1 KB.
    const unsigned short* ga[2];
    unsigned short* la[2];
    #pragma unroll
    for (int c = 0; c < 2; ++c) {
        int p = c * 256 + wave * 64 + lane;
        int row = p >> 2;
        int oct = (p & 3) ^ ((row >> 1) & 3);
        ga[c] = A + (size_t)(m0 + row) * K_DIM + oct * 8;
        la[c] = As + (size_t)(c * 256 + wave * 64) * 8;   // wave-uniform base
    }

    // B staging thread map
    const int bk = tid >> 5;          // k 0..7 (+8*it)
    const int bn = (tid & 31) * 4;    // n
    const int bswz = (bn >> 2) & 3;

    for (int k0 = 0; k0 < K_DIM; k0 += BK) {
        async_copy16(ga[0] + k0, la[0]);
        async_copy16(ga[1] + k0, la[1]);
        #pragma unroll
        for (int it = 0; it < 4; ++it) {
            int kk = bk + it * 8;
            float4 v = *reinterpret_cast<const float4*>(
                Wf + (size_t)(k0 + kk) * OUT_F + n0 + bn);
            int kcol = (((kk >> 3) ^ bswz) << 3) + (kk & 7);
            Bs[(bn + 0) * LDK + kcol] = f2bf(v.x);
            Bs[(bn + 1) * LDK + kcol] = f2bf(v.y);
            Bs[(bn + 2) * LDK + kcol] = f2bf(v.z);
            Bs[(bn + 3) * LDK + kcol] = f2bf(v.w);
        }
        __syncthreads();

        bf16x8 af[4], bfr[4];
        #pragma unroll
        for (int i = 0; i < 4; ++i) {
            int row = wm + i * 16 + l16;
            int oph = quad ^ ((row >> 1) & 3);
            af[i] = *reinterpret_cast<const bf16x8*>(&As[(row * 4 + oph) * 8]);
            int nn  = wn + i * 16 + l16;
            int oct = quad ^ ((nn >> 2) & 3);
            bfr[i] = *reinterpret_cast<const bf16x8*>(&Bs[nn * LDK + oct * 8]);
        }
        #pragma unroll
        for (int i = 0; i < 4; ++i)
            #pragma unroll
            for (int j = 0; j < 4; ++j)
                acc[i][j] = __builtin_amdgcn_mfma_f32_16x16x32_bf16(
                    af[i], bfr[j], acc[i][j], 0, 0, 0);
        __syncthreads();
    }

    // Epilogue: C/D layout col = l16, row = quad*4 + r. Fused bias + ReLU.
    #pragma unroll
    for (int j = 0; j < 4; ++j) {
        int col = n0 + wn + j * 16 + l16;
        float bv = bias[col];
        #pragma unroll
        for (int i = 0; i < 4; ++i) {
            int row_base = m0 + wm + i * 16 + quad * 4;
            #pragma unroll
            for (int r = 0; r < 4; ++r)
                out[(size_t)(row_base + r) * OUT_F + col] =
                    fmaxf(acc[i][j][r] + bv, 0.f);
        }
    }
}

extern "C" void kernel_launch(void* const* d_in, const int* in_sizes, int n_in,
                              void* d_out, int out_size, void* d_ws, size_t ws_size,
                              hipStream_t stream) {
    const float* text  = (const float*)d_in[0];   // [64,512,256] f32
    const int*   src   = (const int*)d_in[1];     // [E]
    const int*   dst   = (const int*)d_in[2];     // [E]
    const int*   rel   = (const int*)d_in[3];     // [E]
    const float* bases = (const float*)d_in[4];   // [3,256,256] f32 = [768,256]
    const float* comp  = (const float*)d_in[5];   // [40,3] f32
    const float* bias  = (const float*)d_in[6];   // [256] f32
    float* out = (float*)d_out;

    // Workspace layout (51.64 MB total, within the proven 51.8 MB footprint)
    unsigned short* z = (unsigned short*)d_ws;                 // N*768*2 = 50.33 MB
    int* packed  = (int*)((char*)d_ws + (size_t)N_NODES * K_DIM * 2); // E ints
    int* offsets = packed + N_EDGES;                           // N+1 ints
    int* counts  = offsets + (N_NODES + 1);                    // N ints (-> cursor)

    hipMemsetAsync(counts, 0, (size_t)N_NODES * sizeof(int), stream);

    hist_kernel<<<N_EDGES / 256, 256, 0, stream>>>(dst, counts);
    scan_kernel<<<1, 1024, 0, stream>>>(counts, offsets);
    scatter_kernel<<<N_EDGES / 256, 256, 0, stream>>>(dst, src, rel, counts, packed);
    agg_kernel<<<N_NODES / 4, 256, 0, stream>>>(text, packed, offsets, comp, z);
    gemm_kernel<<<dim3(N_NODES / 128, OUT_F / 128), 256, 0, stream>>>(
        z, bases, bias, out);
}

// Round 4
// 187.772 us; speedup vs baseline: 5.4197x; 1.1464x over previous
//
#include <hip/hip_runtime.h>
#include <cstdint>

// Problem constants (fixed by the reference: B=64,S=512,IN=OUT=256,R=40,NB=3,E=262144)
#define N_NODES 32768
#define IN_F    256
#define OUT_F   256
#define NBASES  3
#define N_EDGES 262144
#define K_DIM   (NBASES * IN_F)    // 768: GEMM reduction dim (b*256 + i)

typedef __attribute__((ext_vector_type(8))) short bf16x8;
typedef __attribute__((ext_vector_type(4))) float f32x4;

__device__ __forceinline__ unsigned short f2bf(float x) {
    union { float f; unsigned int u; } c; c.f = x;
    unsigned int u = c.u;
    u = (u + 0x7FFFu + ((u >> 16) & 1u)) >> 16;   // round-to-nearest-even
    return (unsigned short)u;
}
__device__ __forceinline__ float bf2f(unsigned short h) {
    union { unsigned int u; float f; } c; c.u = ((unsigned int)h) << 16;
    return c.f;
}

__device__ __forceinline__ void async_copy16(const void* g, void* l) {
    __builtin_amdgcn_global_load_lds(
        (const __attribute__((address_space(1))) unsigned int*)g,
        (__attribute__((address_space(3))) unsigned int*)l, 16, 0, 0);
}

// ---------------------------------------------------------------------------
// Prep (fused): blocks [0,8192) convert text f32 -> hb bf16 (elementwise);
// blocks [8192,8384) transpose bases [768,256] f32 -> Wt [256,768] bf16.
// ---------------------------------------------------------------------------
__global__ __launch_bounds__(256) void prep_kernel(
    const float* __restrict__ text,     // [N_NODES, 256] f32
    const float* __restrict__ bases,    // [768, 256] f32
    unsigned short* __restrict__ hb,    // [N_NODES, 256] bf16 (may be null)
    unsigned short* __restrict__ Wt)    // [256, 768] bf16
{
    const int tid = threadIdx.x;
    if (blockIdx.x < 8192) {
        if (!hb) return;
        int i = blockIdx.x * 256 + tid;            // float4 index
        float4 v = reinterpret_cast<const float4*>(text)[i];
        ushort4 o;
        o.x = f2bf(v.x); o.y = f2bf(v.y); o.z = f2bf(v.z); o.w = f2bf(v.w);
        reinterpret_cast<ushort4*>(hb)[i] = o;
    } else {
        int tb = blockIdx.x - 8192;                // [0,192)
        int kb = tb % 24, ob = tb / 24;            // 32-wide tiles
        __shared__ float tile[32][33];
        int c = tid & 31, r8 = tid >> 5;
        #pragma unroll
        for (int i = 0; i < 4; ++i) {
            int r = r8 + 8 * i;
            tile[r][c] = bases[(size_t)(kb * 32 + r) * OUT_F + ob * 32 + c];
        }
        __syncthreads();
        #pragma unroll
        for (int i = 0; i < 4; ++i) {
            int r = r8 + 8 * i;                    // output row within o-tile
            Wt[(size_t)(ob * 32 + r) * K_DIM + kb * 32 + c] = f2bf(tile[c][r]);
        }
    }
}

// ---------------------------------------------------------------------------
// Counting sort of edges by dst: histogram -> scan -> scatter(packed)
// ---------------------------------------------------------------------------
__global__ __launch_bounds__(256) void hist_kernel(
    const int* __restrict__ dst, int* __restrict__ counts)
{
    int e = blockIdx.x * 256 + threadIdx.x;
    atomicAdd(&counts[dst[e]], 1);
}

// Single block, 1024 threads, 32 counters each. Converts counts -> cursor
// in place and writes the exclusive-scan offsets.
__global__ __launch_bounds__(1024) void scan_kernel(
    int* __restrict__ counts,        // in: histogram; out: cursor (in place)
    int* __restrict__ offsets)       // [N_NODES+1]
{
    __shared__ int wsum[16];
    const int tid = threadIdx.x;
    const int wave = tid >> 6, lane = tid & 63;
    const int base = tid * 32;
    int local[32];
    int sum = 0;
    #pragma unroll
    for (int k = 0; k < 32; ++k) { local[k] = counts[base + k]; sum += local[k]; }
    int inc = sum;                            // wave-inclusive scan of sums
    #pragma unroll
    for (int off = 1; off < 64; off <<= 1) {
        int v = __shfl_up(inc, off);
        if (lane >= off) inc += v;
    }
    if (lane == 63) wsum[wave] = inc;
    __syncthreads();
    if (wave == 0 && lane < 16) {             // scan the 16 wave totals
        int v = wsum[lane];
        #pragma unroll
        for (int off = 1; off < 16; off <<= 1) {
            int u = __shfl_up(v, off);
            if (lane >= off) v += u;
        }
        wsum[lane] = v;
    }
    __syncthreads();
    int run = inc - sum + (wave ? wsum[wave - 1] : 0);   // exclusive prefix
    #pragma unroll
    for (int k = 0; k < 32; ++k) {
        offsets[base + k] = run;
        counts[base + k] = run;               // cursor
        run += local[k];
    }
    if (tid == 1023) offsets[N_NODES] = run;  // == N_EDGES
}

__global__ __launch_bounds__(256) void scatter_kernel(
    const int* __restrict__ dst, const int* __restrict__ src,
    const int* __restrict__ rel, int* __restrict__ cursor,
    int* __restrict__ packed)                 // sorted (rel<<16)|src
{
    int e = blockIdx.x * 256 + threadIdx.x;
    int pos = atomicAdd(&cursor[dst[e]], 1);
    packed[pos] = (rel[e] << 16) | src[e];
}

// ---------------------------------------------------------------------------
// Aggregation in INPUT space: z[n, b, i] = sum_{e: dst=n} comp[rel_e,b]*h[src_e,i]
// One wave per dst node; lane owns 4 input features. bf16-h variant gathers
// ushort4 (8 B/lane/edge), 2 edges per inner step for MLP.
// ---------------------------------------------------------------------------
__global__ __launch_bounds__(256) void agg_bf16_kernel(
    const unsigned short* __restrict__ hb,    // [N_NODES, 256] bf16
    const int* __restrict__ packed,           // sorted by dst
    const int* __restrict__ offsets,          // [N_NODES+1]
    const float* __restrict__ comp,           // [40, 3]
    unsigned short* __restrict__ z)           // [N_NODES, 768] bf16
{
    __shared__ float compS[128];
    if (threadIdx.x < 120) compS[threadIdx.x] = comp[threadIdx.x];
    __syncthreads();

    const int node = blockIdx.x * 4 + (threadIdx.x >> 6);
    const int lane = threadIdx.x & 63;
    const int start = offsets[node];
    const int end   = offsets[node + 1];

    float a0[4] = {}, a1[4] = {}, a2[4] = {};

    for (int cb = start; cb < end; cb += 64) {
        int idx = cb + lane;
        int pv = (idx < end) ? packed[idx] : 0;
        int cnt = min(64, end - cb);
        int j = 0;
        for (; j + 2 <= cnt; j += 2) {
            int p0 = __shfl(pv, j);
            int p1 = __shfl(pv, j + 1);
            int s0 = p0 & 0xFFFF, r0 = p0 >> 16;
            int s1 = p1 & 0xFFFF, r1 = p1 >> 16;
            ushort4 u0 = *reinterpret_cast<const ushort4*>(
                hb + (size_t)s0 * IN_F + lane * 4);
            ushort4 u1 = *reinterpret_cast<const ushort4*>(
                hb + (size_t)s1 * IN_F + lane * 4);
            float c00 = compS[r0*3], c01 = compS[r0*3+1], c02 = compS[r0*3+2];
            float c10 = compS[r1*3], c11 = compS[r1*3+1], c12 = compS[r1*3+2];
            float v0[4] = { bf2f(u0.x), bf2f(u0.y), bf2f(u0.z), bf2f(u0.w) };
            float v1[4] = { bf2f(u1.x), bf2f(u1.y), bf2f(u1.z), bf2f(u1.w) };
            #pragma unroll
            for (int k = 0; k < 4; ++k) {
                a0[k] += c00 * v0[k] + c10 * v1[k];
                a1[k] += c01 * v0[k] + c11 * v1[k];
                a2[k] += c02 * v0[k] + c12 * v1[k];
            }
        }
        if (j < cnt) {
            int p0 = __shfl(pv, j);
            int s0 = p0 & 0xFFFF, r0 = p0 >> 16;
            ushort4 u0 = *reinterpret_cast<const ushort4*>(
                hb + (size_t)s0 * IN_F + lane * 4);
            float c00 = compS[r0*3], c01 = compS[r0*3+1], c02 = compS[r0*3+2];
            float v0[4] = { bf2f(u0.x), bf2f(u0.y), bf2f(u0.z), bf2f(u0.w) };
            #pragma unroll
            for (int k = 0; k < 4; ++k) {
                a0[k] += c00 * v0[k];
                a1[k] += c01 * v0[k];
                a2[k] += c02 * v0[k];
            }
        }
    }

    unsigned short* zp = z + (size_t)node * K_DIM + lane * 4;
    ushort4 o;
    o.x = f2bf(a0[0]); o.y = f2bf(a0[1]); o.z = f2bf(a0[2]); o.w = f2bf(a0[3]);
    *reinterpret_cast<ushort4*>(zp) = o;
    o.x = f2bf(a1[0]); o.y = f2bf(a1[1]); o.z = f2bf(a1[2]); o.w = f2bf(a1[3]);
    *reinterpret_cast<ushort4*>(zp + 256) = o;
    o.x = f2bf(a2[0]); o.y = f2bf(a2[1]); o.z = f2bf(a2[2]); o.w = f2bf(a2[3]);
    *reinterpret_cast<ushort4*>(zp + 512) = o;
}

// f32 fallback (used only if ws_size can't fit hb)
__global__ __launch_bounds__(256) void agg_f32_kernel(
    const float* __restrict__ h,
    const int* __restrict__ packed,
    const int* __restrict__ offsets,
    const float* __restrict__ comp,
    unsigned short* __restrict__ z)
{
    __shared__ float compS[128];
    if (threadIdx.x < 120) compS[threadIdx.x] = comp[threadIdx.x];
    __syncthreads();
    const int node = blockIdx.x * 4 + (threadIdx.x >> 6);
    const int lane = threadIdx.x & 63;
    const int start = offsets[node];
    const int end   = offsets[node + 1];
    float a0[4] = {}, a1[4] = {}, a2[4] = {};
    for (int cb = start; cb < end; cb += 64) {
        int idx = cb + lane;
        int pv = (idx < end) ? packed[idx] : 0;
        int cnt = min(64, end - cb);
        for (int j = 0; j < cnt; ++j) {
            int p = __shfl(pv, j);
            int s = p & 0xFFFF, r = p >> 16;
            float c0 = compS[r*3], c1 = compS[r*3+1], c2 = compS[r*3+2];
            float4 v = *reinterpret_cast<const float4*>(
                h + (size_t)s * IN_F + lane * 4);
            a0[0] += c0*v.x; a0[1] += c0*v.y; a0[2] += c0*v.z; a0[3] += c0*v.w;
            a1[0] += c1*v.x; a1[1] += c1*v.y; a1[2] += c1*v.z; a1[3] += c1*v.w;
            a2[0] += c2*v.x; a2[1] += c2*v.y; a2[2] += c2*v.z; a2[3] += c2*v.w;
        }
    }
    unsigned short* zp = z + (size_t)node * K_DIM + lane * 4;
    ushort4 o;
    o.x = f2bf(a0[0]); o.y = f2bf(a0[1]); o.z = f2bf(a0[2]); o.w = f2bf(a0[3]);
    *reinterpret_cast<ushort4*>(zp) = o;
    o.x = f2bf(a1[0]); o.y = f2bf(a1[1]); o.z = f2bf(a1[2]); o.w = f2bf(a1[3]);
    *reinterpret_cast<ushort4*>(zp + 256) = o;
    o.x = f2bf(a2[0]); o.y = f2bf(a2[1]); o.z = f2bf(a2[2]); o.w = f2bf(a2[3]);
    *reinterpret_cast<ushort4*>(zp + 512) = o;
}

// ---------------------------------------------------------------------------
// GEMM: out[m, o] = relu( sum_k z[m,k] * Wt[o,k] + bias[o] )
// M=32768, N=256, K=768. 128x128 tile, BK=32, 4 waves (2x2), MFMA 16x16x32.
// BOTH operands staged via global_load_lds width=16 into an XOR-swizzled
// [row][k-octet] LDS layout (2-way max bank aliasing = free; no staging VALU).
// ---------------------------------------------------------------------------
__global__ __launch_bounds__(256) void gemm_kernel(
    const unsigned short* __restrict__ A,   // z  [32768, 768] bf16
    const unsigned short* __restrict__ Bt,  // Wt [256, 768] bf16
    const float* __restrict__ bias,         // [256]
    float* __restrict__ out)                // [32768, 256] f32
{
    __shared__ __align__(16) unsigned short As[128 * 32];   // 16B slots, swizzled
    __shared__ __align__(16) unsigned short Bs[128 * 32];

    const int tid  = threadIdx.x;
    const int wave = tid >> 6, lane = tid & 63;
    const int quad = lane >> 4, l16 = lane & 15;
    const int wm = (wave & 1) * 64, wn = (wave >> 1) * 64;
    const int m0 = blockIdx.x * 128, n0 = blockIdx.y * 128;

    f32x4 acc[4][4] = {};

    // Staging map: slot p <- logical (row = p>>2, oct = (p&3)^((row>>1)&3)).
    // Each wave: 2 A-loads + 2 B-loads of 1 KB each.
    const unsigned short *ga[2], *gb[2];
    unsigned short *la[2], *lb[2];
    #pragma unroll
    for (int c = 0; c < 2; ++c) {
        int p = c * 256 + wave * 64 + lane;
        int row = p >> 2;
        int oct = (p & 3) ^ ((row >> 1) & 3);
        ga[c] = A  + (size_t)(m0 + row) * K_DIM + oct * 8;
        gb[c] = Bt + (size_t)(n0 + row) * K_DIM + oct * 8;
        la[c] = As + (size_t)(c * 256 + wave * 64) * 8;   // wave-uniform base
        lb[c] = Bs + (size_t)(c * 256 + wave * 64) * 8;
    }

    for (int k0 = 0; k0 < K_DIM; k0 += 32) {
        async_copy16(ga[0] + k0, la[0]);
        async_copy16(ga[1] + k0, la[1]);
        async_copy16(gb[0] + k0, lb[0]);
        async_copy16(gb[1] + k0, lb[1]);
        __syncthreads();

        bf16x8 af[4], bfr[4];
        #pragma unroll
        for (int i = 0; i < 4; ++i) {
            int row = wm + i * 16 + l16;
            int oph = quad ^ ((row >> 1) & 3);
            af[i] = *reinterpret_cast<const bf16x8*>(&As[(row * 4 + oph) * 8]);
            int nn   = wn + i * 16 + l16;
            int oph2 = quad ^ ((nn >> 1) & 3);
            bfr[i] = *reinterpret_cast<const bf16x8*>(&Bs[(nn * 4 + oph2) * 8]);
        }
        #pragma unroll
        for (int i = 0; i < 4; ++i)
            #pragma unroll
            for (int j = 0; j < 4; ++j)
                acc[i][j] = __builtin_amdgcn_mfma_f32_16x16x32_bf16(
                    af[i], bfr[j], acc[i][j], 0, 0, 0);
        __syncthreads();
    }

    // Epilogue: C/D layout col = l16, row = quad*4 + r. Fused bias + ReLU.
    #pragma unroll
    for (int j = 0; j < 4; ++j) {
        int col = n0 + wn + j * 16 + l16;
        float bv = bias[col];
        #pragma unroll
        for (int i = 0; i < 4; ++i) {
            int row_base = m0 + wm + i * 16 + quad * 4;
            #pragma unroll
            for (int r = 0; r < 4; ++r)
                out[(size_t)(row_base + r) * OUT_F + col] =
                    fmaxf(acc[i][j][r] + bv, 0.f);
        }
    }
}

extern "C" void kernel_launch(void* const* d_in, const int* in_sizes, int n_in,
                              void* d_out, int out_size, void* d_ws, size_t ws_size,
                              hipStream_t stream) {
    const float* text  = (const float*)d_in[0];   // [64,512,256] f32
    const int*   src   = (const int*)d_in[1];     // [E]
    const int*   dst   = (const int*)d_in[2];     // [E]
    const int*   rel   = (const int*)d_in[3];     // [E]
    const float* bases = (const float*)d_in[4];   // [3,256,256] f32 = [768,256]
    const float* comp  = (const float*)d_in[5];   // [40,3] f32
    const float* bias  = (const float*)d_in[6];   // [256] f32
    float* out = (float*)d_out;

    // Workspace layout (all chunks 16B-aligned):
    //   z       : N*768*2      = 50,331,648 B
    //   packed  : E*4          =  1,048,576 B
    //   offsets : (N+4)*4      =    131,088 B
    //   counts  : N*4          =    131,072 B
    //   Wt      : 256*768*2    =    393,216 B   -> 52,035,600 B required
    //   hb      : N*256*2      = 16,777,216 B   -> 68,812,816 B optional
    char* p = (char*)d_ws;
    unsigned short* z = (unsigned short*)p;       p += (size_t)N_NODES * K_DIM * 2;
    int* packed  = (int*)p;                       p += (size_t)N_EDGES * 4;
    int* offsets = (int*)p;                       p += (size_t)(N_NODES + 4) * 4;
    int* counts  = (int*)p;                       p += (size_t)N_NODES * 4;
    unsigned short* Wt = (unsigned short*)p;      p += (size_t)OUT_F * K_DIM * 2;
    bool use_bf16_h = (ws_size >= (size_t)(p - (char*)d_ws) + (size_t)N_NODES * IN_F * 2);
    unsigned short* hb = use_bf16_h ? (unsigned short*)p : nullptr;

    hipMemsetAsync(counts, 0, (size_t)N_NODES * sizeof(int), stream);

    prep_kernel<<<8384, 256, 0, stream>>>(text, bases, hb, Wt);
    hist_kernel<<<N_EDGES / 256, 256, 0, stream>>>(dst, counts);
    scan_kernel<<<1, 1024, 0, stream>>>(counts, offsets);
    scatter_kernel<<<N_EDGES / 256, 256, 0, stream>>>(dst, src, rel, counts, packed);
    if (use_bf16_h)
        agg_bf16_kernel<<<N_NODES / 4, 256, 0, stream>>>(hb, packed, offsets, comp, z);
    else
        agg_f32_kernel<<<N_NODES / 4, 256, 0, stream>>>(text, packed, offsets, comp, z);
    gemm_kernel<<<dim3(N_NODES / 128, OUT_F / 128), 256, 0, stream>>>(
        z, Wt, bias, out);
}